// Round 9
// baseline (2180.294 us; speedup 1.0000x reference)
//
#include <hip/hip_runtime.h>

// Problem constants
#define T_STEPS 512
#define BATCH   256
#define DIN     128
#define DH      512
#define DOUT    128
#define RGRP    16         // rowgroups (BATCH/16), one block each

typedef __attribute__((ext_vector_type(8))) short  short8;   // 8 bf16 (4 VGPRs)
typedef __attribute__((ext_vector_type(4))) float  floatx4;  // MFMA acc
typedef __attribute__((ext_vector_type(4))) unsigned short ushort4v;

union Pack8 { short8 s; unsigned short h[8]; };

__device__ __forceinline__ float bf2f(unsigned short u) {
    union { unsigned int i; float f; } v; v.i = ((unsigned int)u) << 16; return v.f;
}
__device__ __forceinline__ unsigned short f2bf(float f) {
    union { float f; unsigned int i; } v; v.f = f;
    unsigned int b = v.i;
    b += 0x7FFFu + ((b >> 16) & 1u);   // RNE
    return (unsigned short)(b >> 16);
}
__device__ __forceinline__ float fast_tanh(float v) {
    float ex = __expf(v + v);
    return 1.f - 2.f / (ex + 1.f);
}

// ---------------------------------------------------------------------------
// Pack row-major fp32 [K][N] into bf16 B-fragment order:
//   Wp[ntile][kc][lane][8], lane = quad*16 + (n&15), j = k&7.
// ---------------------------------------------------------------------------
__global__ void pack_b_kernel(const float* __restrict__ W,
                              unsigned short* __restrict__ Wp, int K, int N) {
    int idx = blockIdx.x * blockDim.x + threadIdx.x;
    if (idx >= K * N) return;
    int k = idx / N, n = idx % N;
    int nt = n >> 4, kc = k >> 5, quad = (k >> 3) & 3, j = k & 7;
    int lane = quad * 16 + (n & 15);
    int KC = K >> 5;
    Wp[((size_t)(nt * KC + kc) * 64 + lane) * 8 + j] = f2bf(W[idx]);
}

// ---------------------------------------------------------------------------
// xproj: xpe holds (xs @ W1x + b1) in the rnn-epilogue consumption layout:
//   xpe[(t*16+rg)][cw 0..7][lane 0..63][ci 0..3][r 0..3]  (ushort each)
// Any consumer reads its addends as b128s at [nt>>2][lane][nt&3][r].
// ---------------------------------------------------------------------------
__global__ __launch_bounds__(256) void xproj_kernel(
        const float* __restrict__ xs,
        const unsigned short* __restrict__ W1xp,
        const float* __restrict__ b1p,
        unsigned short* __restrict__ xpe) {
    const int tid  = threadIdx.x;
    const int lane = tid & 63;
    const int w    = tid >> 6;
    const int m    = lane & 15;
    const int q    = lane >> 4;
    const long row0 = (long)blockIdx.x * 16;
    const float b1 = b1p[0];

    short8 a[4];
#pragma unroll
    for (int kc = 0; kc < 4; ++kc) {
        const float* src = xs + (row0 + m) * DIN + kc * 32 + q * 8;
        Pack8 av;
#pragma unroll
        for (int j = 0; j < 8; ++j) av.h[j] = f2bf(src[j]);
        a[kc] = av.s;
    }

#pragma unroll
    for (int i = 0; i < 8; ++i) {
        const int nt = w * 8 + i;
        floatx4 acc = {0.f, 0.f, 0.f, 0.f};
#pragma unroll
        for (int kc = 0; kc < 4; ++kc) {
            short8 b = *(const short8*)(W1xp + ((size_t)(nt * 4 + kc) * 64 + lane) * 8);
            acc = __builtin_amdgcn_mfma_f32_16x16x32_bf16(a[kc], b, acc, 0, 0, 0);
        }
        ushort4v sv;
#pragma unroll
        for (int r = 0; r < 4; ++r) sv[r] = f2bf(acc[r] + b1);
        *(ushort4v*)&xpe[((size_t)blockIdx.x * 512 +
                          (size_t)(nt >> 2) * 64 + lane) * 16 + (nt & 3) * 4] = sv;
    }
}

// ---------------------------------------------------------------------------
// Recurrence v9 — 4-wave, intrinsic-only MFMA. 16 blocks x 256 threads
// (4 waves, 1/SIMD). Wave w owns ntiles 8w..8w+7 (128 h-cols).
//
// v7/v8 post-mortem: the 4-wave index mapping is verified end-to-end
// (symbolic element trace write->read), yet both failed with ~0.5 absmax.
// The unique shared feature vs all PASSING kernels: INLINE-ASM MFMA at
// 1 wave/SIMD. CDNA MFMA has software-managed wait-state requirements the
// compiler inserts for intrinsics but cannot see inside asm; at 2 waves/
// SIMD (r3, same asm, passed) the sibling wave fills hazard slots, at
// 1 wave/SIMD nothing does -> sporadic corruption. v9 removes ALL inline-
// asm MFMA: gfx950's unified RF lets intrinsic MFMA read AGPR operands
// directly (ISA sec 10), so the "+a" pin gives residency with zero copies
// and full compiler hazard handling.
//   kc 0..5   -> AGPR-pinned (48 tuples, 192 AGPRs), re-pinned at loop top
//                (blocks load-sinking, the r0 failure mode)
//   kc 6..7   -> LDS Wl (64 KB; total LDS 98304 B = the ONLY >64KB opt-in
//                size proven to run, r4)           [LKC=2; fallback LKC=0]
//   kc 8..15  -> streamed from L2 (256 KB/step ~3700 cyc = predicted bound),
//                2-deep double-buffer, rot = t%NS (anti-LICM, r5-proven)
// Pipe model per CU per step: MFMA 2048 | L2 ~3700 | LDS ~2100 | VALU ~700;
// 1 wave/SIMD self-overlap target ~4000 cyc/step.
// h in LDS, A-frag layout, double-buffered, swizzled (verified end-to-end).
// ---------------------------------------------------------------------------
template <int LKC>   // 2 or 0
__global__ __launch_bounds__(256, 1)
void rnn_v9(const unsigned short* __restrict__ xpe,
            const unsigned short* __restrict__ W1hp,
            const float* __restrict__ W2,
            const float* __restrict__ b2p,
            float* __restrict__ out) {
    extern __shared__ unsigned short smem[];
    unsigned short* Hb = smem;              // [2][16 kc][64 slot][8] = 32768 B
    unsigned short* Wl = smem + 16384;      // [LKC][32 nt][64 lane][8]

    const int tid  = threadIdx.x;
    const int lane = tid & 63;
    const int w    = tid >> 6;      // 0..3
    const int m    = lane & 15;
    const int q    = lane >> 4;
    const int rg   = blockIdx.x;

    constexpr int RKC  = 6;             // AGPR-resident kc count (192 AGPRs)
    constexpr int SKC0 = RKC + LKC;     // first streamed kc
    constexpr int NS   = 16 - RKC - LKC;  // 8 (LKC=2) or 10 (LKC=0)

    // ---- AGPR-pinned W1h: kc 0..5 x ntiles 8w..8w+7 ----
    short8 wa[RKC][8];
#pragma unroll
    for (int kc = 0; kc < RKC; ++kc)
#pragma unroll
        for (int i = 0; i < 8; ++i) {
            wa[kc][i] = *(const short8*)(W1hp +
                ((size_t)((8 * w + i) * 16 + kc) * 64 + lane) * 8);
            asm("" : "+a"(wa[kc][i]));   // pin to AGPR class (residency)
        }

    // ---- LDS-resident W1h: kc RKC..RKC+LKC-1 ----
    if (LKC > 0) {
        for (int c = tid; c < LKC * 2048; c += 256) {
            int j  = c >> 11;
            int r2 = c & 2047;
            int nt = r2 >> 6, ln = r2 & 63;
            *(short8*)&Wl[(size_t)c * 8] =
                *(const short8*)(W1hp + ((size_t)(nt * 16 + RKC + j) * 64 + ln) * 8);
        }
    }

    // ---- addressing: A-frag slot swizzle (read side) ----
    const int slot = lane ^ ((lane >> 4) << 2) ^ (((lane >> 3) & 1) << 1);
    int roff = slot * 8;                 // ushort index into current read buf

    // write addresses: value (i, r) -> Hb[widx[i] ^ (r<<3)]
    // col = (8w+i)*16+m -> kc' = 4w + (i>>1), q' = (2i + (m>>3))&3, j' = m&7
    int widx[8];
#pragma unroll
    for (int i = 0; i < 8; ++i) {
        int kcp = 4 * w + (i >> 1);
        int qp  = (2 * i + (m >> 3)) & 3;
        int lp  = 4 * q + 16 * qp;       // lane' at r=0
        int sl  = lp ^ ((lp >> 4) << 2) ^ (((lp >> 3) & 1) << 1);
        widx[i] = kcp * 512 + sl * 8 + (m & 7);
    }

    // ---- h^1 = tanh(xpe[0]) -> buf0 (b1 folded into xpe) ----
    {
        short8 xq[2][2];
#pragma unroll
        for (int g = 0; g < 2; ++g) {
            const unsigned short* xb =
                xpe + ((size_t)rg * 512 + (size_t)(2 * w + g) * 64 + lane) * 16;
            xq[g][0] = ((const short8*)xb)[0];
            xq[g][1] = ((const short8*)xb)[1];
        }
#pragma unroll
        for (int i = 0; i < 8; ++i) {
            int g = i >> 2, ci = i & 3;
            Pack8 ph; ph.s = xq[g][ci >> 1];
#pragma unroll
            for (int r = 0; r < 4; ++r) {
                float v = bf2f(ph.h[(ci & 1) * 4 + r]);
                Hb[widx[i] ^ (r << 3)] = f2bf(fast_tanh(v));
            }
            widx[i] ^= 8192;             // next write -> buf1
        }
    }
    __syncthreads();

#pragma unroll 1
    for (int t = 1; t < T_STEPS; ++t) {
        // Re-pin: keeps wa defined-by-asm inside the loop so the loads can
        // never be sunk/rematerialized from memory (r0 failure mode).
        // Emits no instructions; AGPR class is unchanged.
#pragma unroll
        for (int kc = 0; kc < RKC; ++kc)
#pragma unroll
            for (int i = 0; i < 8; ++i)
                asm("" : "+a"(wa[kc][i]));

        const unsigned short* hrd = Hb + roff;
        const int rot = t % NS;          // streamed-kc rotation (anti-LICM)

        // streamed double-buffer: initial fills skc(rot), skc(rot+1)
        short8 sb[2][8];
#pragma unroll
        for (int c = 0; c < 2; ++c) {
            int x = c + rot; if (x >= NS) x -= NS;
            const int kc = SKC0 + x;
#pragma unroll
            for (int i = 0; i < 8; ++i)
                sb[c][i] = *(const short8*)(W1hp +
                    ((size_t)((8 * w + i) * 16 + kc) * 64 + lane) * 8);
        }

        // xpe[t] prefetch (consumed in the epilogue)
        short8 xq[2][2];
#pragma unroll
        for (int g = 0; g < 2; ++g) {
            const unsigned short* xb = xpe +
                (((size_t)t * 16 + rg) * 512 + (size_t)(2 * w + g) * 64 + lane) * 16;
            xq[g][0] = ((const short8*)xb)[0];
            xq[g][1] = ((const short8*)xb)[1];
        }

        floatx4 acc[8];
#pragma unroll
        for (int i = 0; i < 8; ++i) acc[i] = (floatx4){0.f, 0.f, 0.f, 0.f};

        // ---- AGPR-resident kcs: intrinsic MFMA reads the pinned AGPR
        // operand directly (unified RF) -- compiler owns all hazards ----
#pragma unroll
        for (int kc = 0; kc < RKC; ++kc) {
            short8 a = *(const short8*)&hrd[kc * 512];
#pragma unroll
            for (int i = 0; i < 8; ++i)
                acc[i] = __builtin_amdgcn_mfma_f32_16x16x32_bf16(a, wa[kc][i], acc[i], 0, 0, 0);
        }

        // ---- LDS-resident kcs ----
#pragma unroll
        for (int j = 0; j < LKC; ++j) {
            short8 a = *(const short8*)&hrd[(RKC + j) * 512];
#pragma unroll
            for (int i = 0; i < 8; ++i) {
                short8 b = *(const short8*)&Wl[((size_t)(j * 32 + 8 * w + i) * 64 + lane) * 8];
                acc[i] = __builtin_amdgcn_mfma_f32_16x16x32_bf16(a, b, acc[i], 0, 0, 0);
            }
        }

        // ---- streamed kcs: consume sb[sc&1], refill with skc(sc+2) ----
#pragma unroll
        for (int sc = 0; sc < NS; ++sc) {
            int xa = sc + rot; if (xa >= NS) xa -= NS;
            short8 a = *(const short8*)&hrd[(SKC0 + xa) * 512];
#pragma unroll
            for (int i = 0; i < 8; ++i)
                acc[i] = __builtin_amdgcn_mfma_f32_16x16x32_bf16(a, sb[sc & 1][i], acc[i], 0, 0, 0);
            if (sc + 2 < NS) {
                int x = sc + 2 + rot; if (x >= NS) x -= NS;
                const int kc = SKC0 + x;
#pragma unroll
                for (int i = 0; i < 8; ++i)
                    sb[sc & 1][i] = *(const short8*)(W1hp +
                        ((size_t)((8 * w + i) * 16 + kc) * 64 + lane) * 8);
            }
        }

        // ---- epilogue: h^{t+1} = tanh(acc + xpe[t]) -> other buffer ----
#pragma unroll
        for (int i = 0; i < 8; ++i) {
            const int g = i >> 2, ci = i & 3;
            Pack8 ph; ph.s = xq[g][ci >> 1];
#pragma unroll
            for (int r = 0; r < 4; ++r) {
                float v = acc[i][r] + bf2f(ph.h[(ci & 1) * 4 + r]);
                Hb[widx[i] ^ (r << 3)] = f2bf(fast_tanh(v));
            }
            widx[i] ^= 8192;
        }
        roff ^= 8192;
        __syncthreads();
    }

    // ---- tail: out = h^512 @ W2 + b2; wave w does col-tiles 2w, 2w+1 ----
    const float b2 = b2p[0];
#pragma unroll
    for (int w2t = 0; w2t < 2; ++w2t) {
        const int w2 = 2 * w + w2t;
        floatx4 acc2 = {0.f, 0.f, 0.f, 0.f};
#pragma unroll
        for (int kc = 0; kc < 16; ++kc) {
            short8 av = *(const short8*)&Hb[roff + kc * 512];
            Pack8 bv;
#pragma unroll
            for (int j = 0; j < 8; ++j)
                bv.h[j] = f2bf(W2[(size_t)(kc * 32 + q * 8 + j) * DOUT + w2 * 16 + m]);
            acc2 = __builtin_amdgcn_mfma_f32_16x16x32_bf16(av, bv.s, acc2, 0, 0, 0);
        }
#pragma unroll
        for (int r = 0; r < 4; ++r)
            out[(size_t)(rg * 16 + q * 4 + r) * DOUT + w2 * 16 + m] = acc2[r] + b2;
    }
}

// ---------------------------------------------------------------------------
extern "C" void kernel_launch(void* const* d_in, const int* in_sizes, int n_in,
                              void* d_out, int out_size, void* d_ws, size_t ws_size,
                              hipStream_t stream) {
    const float* xs  = (const float*)d_in[0];
    const float* W1x = (const float*)d_in[1];
    const float* W1h = (const float*)d_in[2];
    const float* b1  = (const float*)d_in[3];
    const float* W2  = (const float*)d_in[4];
    const float* b2  = (const float*)d_in[5];
    float* out = (float*)d_out;

    // ws (bf16 elems): xpe | W1h packed | W1x packed
    unsigned short* xpe  = (unsigned short*)d_ws;
    unsigned short* w1hp = xpe + (size_t)T_STEPS * BATCH * DH;     // 67,108,864
    unsigned short* w1xp = w1hp + (size_t)DH * DH;                 // +262,144

    pack_b_kernel<<<(DH * DH + 255) / 256, 256, 0, stream>>>(W1h, w1hp, DH, DH);
    pack_b_kernel<<<(DIN * DH + 255) / 256, 256, 0, stream>>>(W1x, w1xp, DIN, DH);
    xproj_kernel<<<(T_STEPS * BATCH) / 16, 256, 0, stream>>>(xs, w1xp, b1, xpe);

    // LKC=2: Hb 32768 + Wl 65536 = 98304 B dynamic LDS — the exact size
    // proven to launch in r4 (rnn_skel_big ran). Fallback LKC=0: 32768 B.
    constexpr size_t SMEM_BIG   = 32768 + 2 * 32768;   // 98304
    constexpr size_t SMEM_SMALL = 32768;
    hipError_t e = hipFuncSetAttribute(
        reinterpret_cast<const void*>(&rnn_v9<2>),
        hipFuncAttributeMaxDynamicSharedMemorySize, (int)SMEM_BIG);
    if (e == hipSuccess) {
        rnn_v9<2><<<RGRP, 256, SMEM_BIG, stream>>>(xpe, w1hp, W2, b2, out);
    } else {
        rnn_v9<0><<<RGRP, 256, SMEM_SMALL, stream>>>(xpe, w1hp, W2, b2, out);
    }
}